// Round 6
// baseline (185.341 us; speedup 1.0000x reference)
//
#include <hip/hip_runtime.h>

// Shape fixed by reference: (2,1,160,160,160) fp32, window 11, zero-pad box filter.
// Fields reduced via u=x+y, v=x-y: box{u, v, u^2, v^2} packed in one float4.
// R5: 2 slabs per loop iteration (1.5 barriers/slab), 8-output sliding W/H passes.
#define DIMX 160
#define DIMY 160
#define DIMZ 160
#define BC   2
#define NTOT (BC * DIMZ * DIMY * DIMX)   // 8,192,000
#define PAD  5
#define TS   16                  // tile size in H and W
#define HS   26                  // TS + 2*PAD rows
#define XS4  10                  // stage row stride in float4 (8 used + 2 pad)
#define WPS  17                  // wp row stride in float4 (breaks bank aliasing)
#define CD   20                  // D-chunk per block
#define NCH  (DIMZ / CD)         // 8
#define NTH  (DIMY / TS)         // 10
#define NTW  (DIMX / TS)         // 10
#define NBLK (NCH * BC * NTH * NTW)  // 1600 blocks

static_assert(NTOT == 8192000, "size mismatch");

__device__ __forceinline__ float4 f4add(float4 a, float4 b) {
  return make_float4(a.x + b.x, a.y + b.y, a.z + b.z, a.w + b.w);
}
__device__ __forceinline__ float4 f4sub(float4 a, float4 b) {
  return make_float4(a.x - b.x, a.y - b.y, a.z - b.z, a.w - b.w);
}

// Paired ring update for 2 consecutive slabs; compile-time indices keep ring[] in VGPRs.
#define RING2(K, K2) case K: {                                   \
    sums = f4add(sums, f4sub(SA, ring[K]));  ring[K]  = SA; s1 = sums; \
    sums = f4add(sums, f4sub(SB, ring[K2])); ring[K2] = SB; s2 = sums; \
  } break;

// 8-output sliding 11-tap W window over 24 staged floats (6 b128 reads).
__device__ __forceinline__ void wslide(const float4* __restrict__ st, int rb,
                                       float s_out[8], float ss_out[8]) {
  float t[24];
  float4 q;
  q = st[rb    ]; t[0]=q.x;  t[1]=q.y;  t[2]=q.z;  t[3]=q.w;
  q = st[rb + 1]; t[4]=q.x;  t[5]=q.y;  t[6]=q.z;  t[7]=q.w;
  q = st[rb + 2]; t[8]=q.x;  t[9]=q.y;  t[10]=q.z; t[11]=q.w;
  q = st[rb + 3]; t[12]=q.x; t[13]=q.y; t[14]=q.z; t[15]=q.w;
  q = st[rb + 4]; t[16]=q.x; t[17]=q.y; t[18]=q.z; t[19]=q.w;
  q = st[rb + 5]; t[20]=q.x; t[21]=q.y; t[22]=q.z; t[23]=q.w;
  float s = 0.f, ss = 0.f;
#pragma unroll
  for (int j = 3; j <= 13; ++j) { s += t[j]; ss = fmaf(t[j], t[j], ss); }
  s_out[0] = s; ss_out[0] = ss;
#pragma unroll
  for (int k = 1; k < 8; ++k) {
    const float nw = t[13 + k], od = t[2 + k];
    s += nw - od;
    ss = fmaf(nw, nw, fmaf(-od, od, ss));
    s_out[k] = s; ss_out[k] = ss;
  }
}

__device__ __forceinline__ float ssim_term(float4 sm, float inv, float c1, float c2) {
  const float mu_u = sm.x * inv, mu_v = sm.y * inv;
  const float Euu  = sm.z * inv, Evv  = sm.w * inv;
  const float P = mu_u * mu_u, Q = mu_v * mu_v;
  const float sgu = Euu - P, sgv = Evv - Q;
  const float num = (0.5f * (P - Q) + c1) * (0.5f * (sgu - sgv) + c2);
  const float den = (0.5f * (P + Q) + c1) * (0.5f * (sgu + sgv) + c2);
  const float ssim = num * __builtin_amdgcn_rcpf(den + 1e-8f);
  const float val  = 0.5f * (1.f - ssim);
  return fminf(fmaxf(val, 0.f), 1.f);
}

__global__ __launch_bounds__(256) void fused_ssim(const float* __restrict__ X,
                                                  const float* __restrict__ Y,
                                                  float* __restrict__ pssim,
                                                  float* __restrict__ pl1) {
  __shared__ float4 usA[HS * XS4], vsA[HS * XS4];   // staged u,v slab A
  __shared__ float4 usB[HS * XS4], vsB[HS * XS4];   // staged u,v slab B
  __shared__ float4 wpA[HS * WPS], wpB[HS * WPS];   // W-passed {su,sv,suu,svv}
  __shared__ float4 SbA[TS * TS],  SbB[TS * TS];    // H-passed per-voxel fields

  const int tid = threadIdx.x;
  const int bx  = blockIdx.x;
  const int tw  = bx % NTW;
  const int th  = (bx / NTW) % NTH;
  const int b   = (bx / (NTW * NTH)) % BC;
  const int ch  =  bx / (NTW * NTH * BC);
  const int h0 = th * TS, w0 = tw * TS, c0 = ch * CD;
  const size_t bbase = (size_t)b * (DIMZ * DIMY * DIMX);

  // staging decomposition: 208 threads = 26 rows x 8 float4-cols (w0-8 .. w0+23)
  const int sr  = tid >> 3, sc4 = tid & 7;
  const int sgh = h0 - PAD + sr;
  const int sgw = w0 - 8 + (sc4 << 2);
  const bool sok = (tid < 208) && ((unsigned)sgh < (unsigned)DIMY) &&
                   ((unsigned)sgw < (unsigned)DIMX);
  const bool l1own = (sr >= PAD) && (sr < PAD + TS) && (sc4 >= 2) && (sc4 < 6);
  const size_t sgoff = bbase + (size_t)sgh * DIMX + sgw;

  // W-pass decomposition: 104 threads = 2 slabs x 26 rows x 2 groups (8 outputs each)
  const int wsl = tid / 52;                 // slab select
  const int wi  = tid - wsl * 52;
  const int wr  = wi >> 1, wg = wi & 1;

  // H-pass decomposition: 64 threads = 2 slabs x 16 cols x 2 halves (8 outputs each)
  const int hsl  = tid >> 5;
  const int hw   = tid & 15, hhalf = (tid >> 4) & 1;

  float4 ring[11];
#pragma unroll
  for (int k = 0; k < 11; ++k) ring[k] = make_float4(0.f, 0.f, 0.f, 0.f);
  float4 sums = make_float4(0.f, 0.f, 0.f, 0.f);
  float l1loc = 0.f, ssloc = 0.f;

  const float inv = 1.0f / 1331.0f;             // 1/11^3
  const float c1  = 0.01f / (4096.f * 4096.f);  // K1 / data_range^2 (faithful to ref)
  const float c2  = 0.03f / (4096.f * 4096.f);

  // prefetch first two slabs (d = c0-5, c0-4) into regs
  float4 xqA = make_float4(0.f,0.f,0.f,0.f), yqA = xqA, xqB = xqA, yqB = xqA;
  if (sok) {
    if ((unsigned)(c0 - PAD) < (unsigned)DIMZ) {
      const size_t g = sgoff + (size_t)(c0 - PAD) * (DIMY * DIMX);
      xqA = *(const float4*)(X + g);
      yqA = *(const float4*)(Y + g);
    }
    if ((unsigned)(c0 - PAD + 1) < (unsigned)DIMZ) {
      const size_t g = sgoff + (size_t)(c0 - PAD + 1) * (DIMY * DIMX);
      xqB = *(const float4*)(X + g);
      yqB = *(const float4*)(Y + g);
    }
  }

  int ph = (c0 + 6) % 11;   // ring phase of slab d at loop top; uniform scalar

  for (int d = c0 - PAD; d < c0 + CD + PAD; d += 2) {
    const bool dvalA = (unsigned)d       < (unsigned)DIMZ;
    const bool dvalB = (unsigned)(d + 1) < (unsigned)DIMZ;

    // --- stage both slabs from prefetched regs; fuse smooth-L1; prefetch d+2,d+3 ---
    if (tid < 208) {
      if (dvalA) {
        const float4 u = f4add(xqA, yqA), v = f4sub(xqA, yqA);
        usA[sr * XS4 + sc4] = u;
        vsA[sr * XS4 + sc4] = v;
        if (l1own && d >= c0 && d < c0 + CD) {
          const float a0 = fabsf(v.x), a1 = fabsf(v.y);
          const float a2 = fabsf(v.z), a3 = fabsf(v.w);
          l1loc += (a0 < 1.f) ? 0.5f * a0 * a0 : a0 - 0.5f;
          l1loc += (a1 < 1.f) ? 0.5f * a1 * a1 : a1 - 0.5f;
          l1loc += (a2 < 1.f) ? 0.5f * a2 * a2 : a2 - 0.5f;
          l1loc += (a3 < 1.f) ? 0.5f * a3 * a3 : a3 - 0.5f;
        }
      }
      if (dvalB) {
        const float4 u = f4add(xqB, yqB), v = f4sub(xqB, yqB);
        usB[sr * XS4 + sc4] = u;
        vsB[sr * XS4 + sc4] = v;
        if (l1own && (d + 1) >= c0 && (d + 1) < c0 + CD) {
          const float a0 = fabsf(v.x), a1 = fabsf(v.y);
          const float a2 = fabsf(v.z), a3 = fabsf(v.w);
          l1loc += (a0 < 1.f) ? 0.5f * a0 * a0 : a0 - 0.5f;
          l1loc += (a1 < 1.f) ? 0.5f * a1 * a1 : a1 - 0.5f;
          l1loc += (a2 < 1.f) ? 0.5f * a2 * a2 : a2 - 0.5f;
          l1loc += (a3 < 1.f) ? 0.5f * a3 * a3 : a3 - 0.5f;
        }
      }
      xqA = make_float4(0.f,0.f,0.f,0.f); yqA = xqA; xqB = xqA; yqB = xqA;
      if (sok) {
        if ((unsigned)(d + 2) < (unsigned)DIMZ) {
          const size_t g = sgoff + (size_t)(d + 2) * (DIMY * DIMX);
          xqA = *(const float4*)(X + g);   // in flight across the 3 barriers below
          yqA = *(const float4*)(Y + g);
        }
        if ((unsigned)(d + 3) < (unsigned)DIMZ) {
          const size_t g = sgoff + (size_t)(d + 3) * (DIMY * DIMX);
          xqB = *(const float4*)(X + g);
          yqB = *(const float4*)(Y + g);
        }
      }
    }
    __syncthreads();

    // --- W-pass, both slabs: 2 x 52 threads x 8 sliding outputs ---
    if (tid < 104) {
      const bool dv = wsl ? dvalB : dvalA;
      if (dv) {
        const float4* us = wsl ? usB : usA;
        const float4* vs = wsl ? vsB : vsA;
        float4*       wp = wsl ? wpB : wpA;
        const int rb = wr * XS4 + (wg << 1);
        float su[8], suu[8], sv[8], svv[8];
        wslide(us, rb, su, suu);
        wslide(vs, rb, sv, svv);
        const int o = wr * WPS + (wg << 3);
#pragma unroll
        for (int k = 0; k < 8; ++k)
          wp[o + k] = make_float4(su[k], sv[k], suu[k], svv[k]);
      }
    }
    __syncthreads();

    // --- H-pass, both slabs: 2 x 32 threads x 8 sliding outputs ---
    if (tid < 64) {
      const bool dv = hsl ? dvalB : dvalA;
      if (dv) {
        const float4* wp = hsl ? wpB : wpA;
        float4*       Sb = hsl ? SbB : SbA;
        const int base = (hhalf << 3) * WPS + hw;
        float4 T[7];
        float4 S = make_float4(0.f, 0.f, 0.f, 0.f);
#pragma unroll
        for (int j = 0; j < 7; ++j) { T[j] = wp[base + j * WPS]; S = f4add(S, T[j]); }
#pragma unroll
        for (int j = 7; j <= 10; ++j) S = f4add(S, wp[base + j * WPS]);
        Sb[((hhalf << 3) + 0) * TS + hw] = S;
#pragma unroll
        for (int k = 1; k < 8; ++k) {
          S = f4sub(f4add(S, wp[base + (10 + k) * WPS]), T[k - 1]);
          Sb[((hhalf << 3) + k) * TS + hw] = S;
        }
      }
    }
    __syncthreads();

    // --- redistribute + paired D-ring update + SSIM for both slabs ---
    float4 SA = make_float4(0.f, 0.f, 0.f, 0.f), SB = SA;
    if (dvalA) SA = SbA[tid];
    if (dvalB) SB = SbB[tid];
    float4 s1 = SA, s2 = SA;
    switch (ph) {
      RING2(0,1) RING2(1,2) RING2(2,3) RING2(3,4) RING2(4,5) RING2(5,6)
      RING2(6,7) RING2(7,8) RING2(8,9) RING2(9,10) RING2(10,0)
    }
    ph += 2; if (ph >= 11) ph -= 11;
    if (d >= c0 + PAD) {           // both output voxels d-5, d-4 in [c0, c0+CD)
      ssloc += ssim_term(s1, inv, c1, c2);
      ssloc += ssim_term(s2, inv, c1, c2);
    }
  }

  // --- block reduction -> per-block partials ---
#pragma unroll
  for (int off = 32; off > 0; off >>= 1) {
    ssloc += __shfl_down(ssloc, off, 64);
    l1loc += __shfl_down(l1loc, off, 64);
  }
  __syncthreads();                 // LDS compute use done; reuse usA as scratch
  float* scr = (float*)usA;
  const int lane = tid & 63, wv = tid >> 6;
  if (lane == 0) {
    scr[wv * 2]     = ssloc;
    scr[wv * 2 + 1] = l1loc;
  }
  __syncthreads();
  if (tid == 0) {
    pssim[bx] = scr[0] + scr[2] + scr[4] + scr[6];
    pl1[bx]   = scr[1] + scr[3] + scr[5] + scr[7];
  }
}

// Final: reduce 1600 + 1600 partials in double, emit scalar loss.
__global__ __launch_bounds__(256) void final_reduce(const float* __restrict__ pssim,
                                                    const float* __restrict__ pl1,
                                                    float* __restrict__ out) {
  double s = 0.0, l = 0.0;
  for (int i = threadIdx.x; i < NBLK; i += 256) {
    s += (double)pssim[i];
    l += (double)pl1[i];
  }
#pragma unroll
  for (int off = 32; off > 0; off >>= 1) {
    s += __shfl_down(s, off, 64);
    l += __shfl_down(l, off, 64);
  }
  __shared__ double sm[8];
  const int lane = threadIdx.x & 63, wv = threadIdx.x >> 6;
  if (lane == 0) { sm[wv * 2] = s; sm[wv * 2 + 1] = l; }
  __syncthreads();
  if (threadIdx.x == 0) {
    const double ssm = (sm[0] + sm[2] + sm[4] + sm[6]) / (double)NTOT;
    const double l1m = (sm[1] + sm[3] + sm[5] + sm[7]) / (double)NTOT;
    out[0] = (float)(0.85 * ssm + 0.15 * l1m);
  }
}

extern "C" void kernel_launch(void* const* d_in, const int* in_sizes, int n_in,
                              void* d_out, int out_size, void* d_ws, size_t ws_size,
                              hipStream_t stream) {
  const float* X = (const float*)d_in[0];
  const float* Y = (const float*)d_in[1];
  float* out = (float*)d_out;

  float* pssim = (float*)d_ws;        // NBLK floats
  float* pl1   = pssim + NBLK;        // NBLK floats

  fused_ssim<<<NBLK, 256, 0, stream>>>(X, Y, pssim, pl1);
  final_reduce<<<1, 256, 0, stream>>>(pssim, pl1, out);
}